// Round 1
// baseline (161.830 us; speedup 1.0000x reference)
//
#include <hip/hip_runtime.h>

// Problem constants
#define D 32
#define K 8
#define NPAIR 36
#define PROWS 576              // packed (4-padded triangular) floats per matrix

// ws layout (float offsets)
#define PMOFF 0                // packed invLc, 8 x 576
#define WOFF 4608              // w_k = invLc_k mu_k, 8 x 32
#define C2OFF 4864             // (c'_t - cmax) * log2(e), 36
#define CMAXOFF 4900
#define TICKOFF 4904           // last-block ticket (unsigned), zeroed by setup
#define PARTOFF 13120          // per-block partial sums (<=1024)

typedef float v2f __attribute__((ext_vector_type(2)));

__host__ __device__ constexpr int gidx(int i, int j) {  // i<=j packed pair index
    return i * 8 + j - i * (i + 1) / 2;
}
__host__ __device__ constexpr int proff(int r) {        // packed row offset
    return 4 * (r / 4 + 1) * (2 * (r / 4) + (r % 4));
}

// ---------------------------------------------------------------------------
// setup (fused setup1+setup2): ONE 512-thread block, 8 wave-groups (one per
// cluster k). All intermediates live in LDS/registers:
//   - L staged into sA, A = L L^T + I computed via registers, written back
//   - Cholesky IN PLACE over sA (lower triangle becomes Lc)
//   - invLc column held in per-lane registers -> packed M written directly
//   - w_k via forward-substitution Lc w = mu (width-32 shuffle broadcast)
//   - pair phase (old setup2) reads Lc straight from LDS - no global roundtrip
// Removes: 1 launch, 32KB Lc write + 32KB staged re-read, setup2 staging wait.
// ---------------------------------------------------------------------------
__global__ __launch_bounds__(512) void setup_kernel(
    const float* __restrict__ mu, const float* __restrict__ L,
    const float* __restrict__ weights, float* __restrict__ ws)
{
    __shared__ float sA[K][D][D + 1];    // 33.8 KB: L staging -> A -> Lc (in place)
    __shared__ float sMu[K * D];
    __shared__ float sLogw[K];
    __shared__ float sCp[NPAIR];
    __shared__ float sCmax;

    const int tid = threadIdx.x;
    const int k = tid >> 6;          // wave-group = cluster (waves are 64-aligned)
    const int t64 = tid & 63;
    const int i = t64 & 31;          // both half-waves duplicate (benign, as before)

    if (tid < K * D) sMu[tid] = mu[tid];
    for (int e = t64; e < D * D; e += 64) sA[k][e >> 5][e & 31] = L[k * D * D + e];
    __syncthreads();

    // A = L L^T + I : compute into registers (sA still holds L), then write back
    float areg[16];
    #pragma unroll
    for (int q = 0; q < 16; ++q) {
        const int e = t64 + 64 * q;
        const int a = e >> 5, c = e & 31;
        float s = (a == c) ? 1.0f : 0.0f;
        #pragma unroll
        for (int b = 0; b < D; ++b) s = fmaf(sA[k][a][b], sA[k][c][b], s);
        areg[q] = s;
    }
    __syncthreads();
    #pragma unroll
    for (int q = 0; q < 16; ++q) {
        const int e = t64 + 64 * q;
        sA[k][e >> 5][e & 31] = areg[q];
    }
    __syncthreads();

    // In-place Cholesky: row j of sA becomes Lc row j at step j. Safe because
    // original A entries [j][b<j] were last read at step b, and [i][j] (i>j)
    // is untouched until its own row is written.
    float lrow[D];
    #pragma unroll
    for (int j = 0; j < D; ++j) {
        if (i == j) {
            float s = sA[k][j][j];
            #pragma unroll
            for (int b = 0; b < j; ++b) s = fmaf(-lrow[b], lrow[b], s);
            const float d = sqrtf(s);
            lrow[j] = d;
            #pragma unroll
            for (int b = 0; b < j; ++b) sA[k][j][b] = lrow[b];
            sA[k][j][j] = d;
        }
        __syncthreads();
        if (i > j) {
            float s = sA[k][i][j];
            #pragma unroll
            for (int b = 0; b < j; ++b) s = fmaf(-lrow[b], sA[k][j][b], s);
            lrow[j] = s / sA[k][j][j];
        }
    }
    __syncthreads();

    // invLc column j in registers; packed M written directly (same values/order
    // as before). col[b]=0 for b<j by construction (lower-triangular inverse).
    {
        const int j = i;
        float col[D];
        #pragma unroll
        for (int ii = 0; ii < D; ++ii) {
            float s = (ii == j) ? 1.0f : 0.0f;
            #pragma unroll
            for (int b = 0; b < ii; ++b) s = fmaf(-sA[k][ii][b], col[b], s);
            const float cii = s / sA[k][ii][ii];
            col[ii] = cii;
            const int w4 = 4 * (ii / 4 + 1);
            if (j < w4) ws[PMOFF + k * PROWS + proff(ii) + j] = cii;
        }
    }

    // w_k: forward-substitution Lc w = mu (== invLc * mu), width-32 broadcast
    {
        float s = sMu[k * D + i];
        #pragma unroll
        for (int j2 = 0; j2 < D; ++j2) {
            const float wj = __shfl(s, j2, 32) / sA[k][j2][j2];
            if (i == j2) ws[WOFF + k * D + i] = wj;
            if (i > j2) s = fmaf(-sA[k][i][j2], wj, s);
        }
    }
    __syncthreads();

    // ---- pair phase (old setup2), Lc read straight from LDS ----
    if (tid == 0) {   // log-softmax of weights; also zero the finish ticket
        float wl[K];
        #pragma unroll
        for (int t = 0; t < K; ++t) wl[t] = weights[t];
        float m = -INFINITY;
        #pragma unroll
        for (int t = 0; t < K; ++t) m = fmaxf(m, wl[t]);
        float s = 0.0f;
        #pragma unroll
        for (int t = 0; t < K; ++t) s += expf(wl[t] - m);
        const float lse = m + logf(s);
        #pragma unroll
        for (int t = 0; t < K; ++t) sLogw[t] = wl[t] - lse;
        *(unsigned int*)(ws + TICKOFF) = 0u;
    }
    __syncthreads();

    if (tid < NPAIR) {
        int tt = tid, pi = 0;
        while (tt >= (K - pi)) { tt -= (K - pi); ++pi; }
        const int pj = pi + tt;
        const float LOG2PI = 1.8378770664093453f;
        float sumlogS = 0.0f, logdetsig = 0.0f;
        #pragma unroll
        for (int r = 0; r < D; ++r) {
            const float di = sA[pi][r][r], dj = sA[pj][r][r];
            sumlogS += logf(di + dj);
            logdetsig -= logf(1.0f / di + 1.0f / dj);
        }
        float v[D];
        float quad_acc = 0.0f;
        #pragma unroll
        for (int r = 0; r < D; ++r) {
            const float d0 = sMu[pi * D + r] - sMu[pj * D + r];
            float s = d0;
            #pragma unroll
            for (int b = 0; b < r; ++b)
                s = fmaf(-(sA[pi][r][b] + sA[pj][r][b]), v[b], s);
            v[r] = s / (sA[pi][r][r] + sA[pj][r][r]);
            quad_acc = fmaf(d0, v[r], quad_acc);
        }
        const float quad = -0.5f * quad_acc;
        float c = quad - 0.5f * sumlogS - (float)D * LOG2PI - 0.5f * logdetsig
                  + sLogw[pi] + sLogw[pj];
        if (pi < pj) c += 0.6931471805599453f;   // off-diagonal multiplicity 2
        sCp[tid] = c;
    }
    __syncthreads();
    if (tid == 0) {
        float m = -INFINITY;
        for (int t = 0; t < NPAIR; ++t) m = fmaxf(m, sCp[t]);
        sCmax = m;
        ws[CMAXOFF] = m;
    }
    __syncthreads();
    if (tid < NPAIR)
        ws[C2OFF + tid] = (sCp[tid] - sCmax) * 1.4426950408889634f;
}

// ---------------------------------------------------------------------------
// main v8: compute core is the R10 winner VERBATIM (2 waves / 128 samples,
// rh-parity split, LDS Gram exchange). New: finish kernel folded in via
// device-scope last-block ticket (store partial, release fence, atomicAdd;
// winner block reduces the partials and writes out). Ticket pre-zeroed by
// setup_kernel each iteration, so re-poison semantics are respected.
// ---------------------------------------------------------------------------
#define XCHG 4864   // float2-exchange area reuses sBig after M reads complete

__global__ __launch_bounds__(128, 2) void main_kernel(
    const float* __restrict__ X, const float* __restrict__ cst,
    float* __restrict__ partials, float* __restrict__ out,
    unsigned int* __restrict__ ticket, int nsamp, int nblk)
{
    __shared__ __align__(16) float sBig[XCHG];   // packed M (4608f) / G-exchange
    __shared__ __align__(16) float sW[K * D];
    __shared__ float sC2[NPAIR];
    __shared__ int sIsLast;
    __shared__ float sRed[2];
    const int tid = threadIdx.x;
    const int wv = tid >> 6;        // wave id within block
    const int lane = tid & 63;

    const int n0 = blockIdx.x * 128 + lane;
    const int n1 = n0 + 64;
    const int m0 = (n0 < nsamp) ? n0 : 0;     // branchless clamps
    const int m1 = (n1 < nsamp) ? n1 : 0;

    // x for both samples, column-pair packed
    v2f xa[16], xb[16];
    {
        const float4* Xv0 = (const float4*)(X + m0 * D);
        const float4* Xv1 = (const float4*)(X + m1 * D);
        #pragma unroll
        for (int q = 0; q < 8; ++q) {
            const float4 t0 = Xv0[q];
            xa[2 * q]     = (v2f){t0.x, t0.y};
            xa[2 * q + 1] = (v2f){t0.z, t0.w};
            const float4 t1 = Xv1[q];
            xb[2 * q]     = (v2f){t1.x, t1.y};
            xb[2 * q + 1] = (v2f){t1.z, t1.w};
        }
    }

    {   // stage packed M + w + c2 into LDS
        const float4* src = (const float4*)cst;
        float4* dst = (float4*)sBig;
        for (int e = tid; e < K * PROWS / 4; e += 128) dst[e] = src[e];
        const float4* srcw = (const float4*)(cst + WOFF);
        float4* dstw = (float4*)sW;
        if (tid < K * D / 4) dstw[tid] = srcw[tid];
        if (tid < NPAIR) sC2[tid] = cst[C2OFF + tid];
    }
    __syncthreads();

    v2f G2[NPAIR];   // this wave's PARTIAL Gram (rows with rh%2 == wv)
    #pragma unroll
    for (int t = 0; t < NPAIR; ++t) G2[t] = (v2f){0.0f, 0.0f};

    #pragma unroll
    for (int rh = 0; rh < 8; ++rh) {
        if ((rh & 1) == wv) {               // wave-uniform gate
            #pragma unroll
            for (int rr = 0; rr < 4; ++rr) {
                const int r = 4 * rh + rr;
                v2f ya[K], yb[K];
                #pragma unroll
                for (int k = 0; k < K; ++k) {
                    const float wvv = sW[k * D + r];
                    v2f a0 = (v2f){-wvv, 0.0f};
                    v2f a1 = (v2f){-wvv, 0.0f};
                    const float* Mr = sBig + k * PROWS + proff(r);
                    #pragma unroll
                    for (int c4 = 0; c4 <= rh; ++c4) {
                        const float4 m4 = *(const float4*)(Mr + 4 * c4);
                        const v2f mlo = (v2f){m4.x, m4.y};   // natural reg pairs
                        const v2f mhi = (v2f){m4.z, m4.w};
                        a0 = __builtin_elementwise_fma(mlo, xa[2 * c4],     a0);
                        a1 = __builtin_elementwise_fma(mlo, xb[2 * c4],     a1);
                        a0 = __builtin_elementwise_fma(mhi, xa[2 * c4 + 1], a0);
                        a1 = __builtin_elementwise_fma(mhi, xb[2 * c4 + 1], a1);
                    }
                    ya[k] = a0;  yb[k] = a1;
                }
                v2f y2[K];
                #pragma unroll
                for (int k = 0; k < K; ++k)
                    y2[k] = (v2f){ya[k].x + ya[k].y, yb[k].x + yb[k].y};
                #pragma unroll
                for (int pi = 0; pi < K; ++pi)
                    #pragma unroll
                    for (int pj = pi; pj < K; ++pj)
                        G2[gidx(pi, pj)] = __builtin_elementwise_fma(
                            y2[pi], y2[pj], G2[gidx(pi, pj)]);
            }
        }
    }

    __syncthreads();   // all M reads complete; sBig reusable for exchange

    // wave 1 publishes partial Gram: float2 element at index t*65 + lane
    if (wv == 1) {
        float2* xch = (float2*)sBig;
        #pragma unroll
        for (int t = 0; t < NPAIR; ++t)
            xch[t * 65 + lane] = make_float2(G2[t].x, G2[t].y);
    }
    __syncthreads();

    // wave 0: combine, 36-term exp sum for both samples, reduce, store
    if (wv == 0) {
        const float2* xch = (const float2*)sBig;
        #pragma unroll
        for (int t = 0; t < NPAIR; ++t) {
            const float2 g = xch[t * 65 + lane];
            G2[t] += (v2f){g.x, g.y};
        }

        v2f acc2 = (v2f){0.0f, 0.0f};
        const float NH = -0.72134752044448170f;   // -0.5*log2(e)
        #pragma unroll
        for (int pi = 0; pi < K; ++pi)
            #pragma unroll
            for (int pj = pi; pj < K; ++pj) {
                const v2f q2 = __builtin_elementwise_fma(
                    (v2f){2.0f, 2.0f}, G2[gidx(pi, pj)],
                    G2[gidx(pi, pi)] + G2[gidx(pj, pj)]);
                const float c = sC2[gidx(pi, pj)];
                const v2f e2 = __builtin_elementwise_fma((v2f){NH, NH}, q2,
                                                         (v2f){c, c});
                acc2.x += exp2f(e2.x);
                acc2.y += exp2f(e2.y);
            }
        float acc = ((n0 < nsamp) ? acc2.x : 0.0f)
                  + ((n1 < nsamp) ? acc2.y : 0.0f);

        #pragma unroll
        for (int s = 1; s < 64; s <<= 1) acc += __shfl_xor(acc, s, 64);
        if (lane == 0) {
            partials[blockIdx.x] = acc;
            __threadfence();                          // release partial
            const unsigned prev = atomicAdd(ticket, 1u);   // device scope (G12)
            sIsLast = (prev == (unsigned)(nblk - 1)) ? 1 : 0;
        }
    }
    __syncthreads();

    // last block to finish performs the final reduction (was finish_kernel)
    if (sIsLast) {
        __threadfence();                              // acquire partials
        float a2 = 0.0f;
        for (int e = tid; e < nblk; e += 128) a2 += partials[e];
        #pragma unroll
        for (int s = 1; s < 64; s <<= 1) a2 += __shfl_xor(a2, s, 64);
        if (lane == 0) sRed[wv] = a2;
        __syncthreads();
        if (tid == 0) out[0] = cst[CMAXOFF] + logf(sRed[0] + sRed[1]);
    }
}

extern "C" void kernel_launch(void* const* d_in, const int* in_sizes, int n_in,
                              void* d_out, int out_size, void* d_ws, size_t ws_size,
                              hipStream_t stream) {
    const float* X = (const float*)d_in[0];
    const float* mu = (const float*)d_in[1];
    const float* L = (const float*)d_in[2];
    const float* w = (const float*)d_in[3];
    float* wsf = (float*)d_ws;
    float* out = (float*)d_out;

    const int nsamp = in_sizes[0] / D;
    const int nblk = (nsamp + 127) / 128;   // 128 samples per 2-wave block

    setup_kernel<<<1, 512, 0, stream>>>(mu, L, w, wsf);
    main_kernel<<<nblk, 128, 0, stream>>>(X, wsf, wsf + PARTOFF, out,
                                          (unsigned int*)(wsf + TICKOFF),
                                          nsamp, nblk);
}